// Round 12
// baseline (144.861 us; speedup 1.0000x reference)
//
#include <hip/hip_runtime.h>

// DIAGNOSTIC ROUND: 4 passes over the full output in ONE dispatch so the
// kernel's own rocprof counter row rises above the harness's 41-us fills.
// Pass p of block b processes super-tile (b + 227p) % 909 (bijective per
// pass, addresses differ per pass -> no LICM collapse; identical values
// written -> benign). w staged once per block; passes 2-4 are staging-free.
// Per-tile math identical to the R8 kernel (passed, absmax 0.25).

#define NTOT 116250
#define DDIM 128
#define FILT 64
#define NPASS 4
#define NTILES 909   // super-tiles of 128 n
#define ROT 227

typedef __bf16 bf16x8 __attribute__((ext_vector_type(8)));
typedef float f32x4 __attribute__((ext_vector_type(4)));
typedef float f32x2 __attribute__((ext_vector_type(2)));

__global__ __launch_bounds__(256) void
conv_dot_kernel(const float* __restrict__ x, const float* __restrict__ w,
                float* __restrict__ out) {
    __shared__ __bf16 lds_w[FILT * DDIM];   // 16 KiB, chunk c at (c ^ (row&15))

    const int tid  = threadIdx.x;
    const int wid  = tid >> 6;
    const int lane = tid & 63;
    const int lq   = lane >> 4;   // 0..3
    const int lr   = lane & 15;   // 0..15

    // ---- cooperative stage: w (fp32, L2-hot) -> LDS (bf16, swizzled), once ----
#pragma unroll
    for (int k = 0; k < 4; ++k) {
        const int chunk = tid + k * 256;
        const int row = chunk >> 4;     // f: 0..63
        const int c   = chunk & 15;     // 0..15
        const float* wp = w + row * DDIM + c * 8;
        f32x4 lo = *reinterpret_cast<const f32x4*>(wp);
        f32x4 hi = *reinterpret_cast<const f32x4*>(wp + 4);
        bf16x8 v;
#pragma unroll
        for (int j = 0; j < 4; ++j) { v[j] = (__bf16)lo[j]; v[j + 4] = (__bf16)hi[j]; }
        *reinterpret_cast<bf16x8*>(&lds_w[row * DDIM + (c ^ (row & 15)) * 8]) = v;
    }
    __syncthreads();

#pragma unroll 1
    for (int p = 0; p < NPASS; ++p) {
        int tl = blockIdx.x + p * ROT;
        if (tl >= NTILES) tl -= NTILES;
        const int nb = tl * 128 + wid * 32;    // wave covers 32 consecutive n

        // ---- both tiles' x bursts issued back-to-back ----
        f32x4 xs[2][8];
#pragma unroll
        for (int t = 0; t < 2; ++t) {
            int nrow = nb + t * 16 + lr;
            if (nrow > NTOT - 1) nrow = NTOT - 1;     // clamp tail loads
            const float* xp = x + (size_t)nrow * DDIM + lq * 8;
#pragma unroll
            for (int kt = 0; kt < 4; ++kt) {
                xs[t][kt * 2]     = *reinterpret_cast<const f32x4*>(xp + kt * 32);
                xs[t][kt * 2 + 1] = *reinterpret_cast<const f32x4*>(xp + kt * 32 + 4);
            }
        }

#pragma unroll
        for (int t = 0; t < 2; ++t) {
            bf16x8 xf[4];
#pragma unroll
            for (int kt = 0; kt < 4; ++kt) {
                bf16x8 b;
#pragma unroll
                for (int j = 0; j < 4; ++j) {
                    b[j]     = (__bf16)xs[t][kt * 2][j];
                    b[j + 4] = (__bf16)xs[t][kt * 2 + 1][j];
                }
                xf[kt] = b;
            }

            f32x4 acc[4] = {};
#pragma unroll
            for (int kt = 0; kt < 4; ++kt) {
#pragma unroll
                for (int ft = 0; ft < 4; ++ft) {
                    const int row = ft * 16 + lr;                 // f
                    const int csw = (kt * 4 + lq) ^ lr;           // (row&15) == lr
                    bf16x8 wf = *reinterpret_cast<const bf16x8*>(&lds_w[row * DDIM + csw * 8]);
                    acc[ft] = __builtin_amdgcn_mfma_f32_16x16x32_bf16(xf[kt], wf, acc[ft], 0, 0, 0);
                }
            }

            // D layout (m89): row = lq*4+reg -> n (A side), col = lr -> f (B side)
            const int n0t = nb + t * 16;
            if (n0t + 15 < NTOT) {
#pragma unroll
                for (int ft = 0; ft < 4; ++ft) {
                    float* pp = out + (size_t)(ft * 16 + lr) * NTOT + n0t + lq * 4;
                    f32x2 v01; v01[0] = acc[ft][0]; v01[1] = acc[ft][1];
                    f32x2 v23; v23[0] = acc[ft][2]; v23[1] = acc[ft][3];
                    *reinterpret_cast<f32x2*>(pp)     = v01;
                    *reinterpret_cast<f32x2*>(pp + 2) = v23;
                }
            } else {
#pragma unroll
                for (int ft = 0; ft < 4; ++ft)
#pragma unroll
                    for (int j = 0; j < 4; ++j) {
                        const int n = n0t + lq * 4 + j;
                        if (n < NTOT)
                            out[(size_t)(ft * 16 + lr) * NTOT + n] = acc[ft][j];
                    }
            }
        }
    }
}

extern "C" void kernel_launch(void* const* d_in, const int* in_sizes, int n_in,
                              void* d_out, int out_size, void* d_ws, size_t ws_size,
                              hipStream_t stream) {
    const float* x = (const float*)d_in[0];   // (1,1,N,D) fp32
    const float* w = (const float*)d_in[1];   // (F,1,1,D) fp32
    float* out = (float*)d_out;               // (F,N) fp32 row-major
    conv_dot_kernel<<<NTILES, 256, 0, stream>>>(x, w, out);
}